// Round 10
// baseline (2881.510 us; speedup 1.0000x reference)
//
#include <hip/hip_runtime.h>
#include <cstdint>
#include <cstddef>

#define XDIM 128
#define HDIM 1024
#define ORS 8192   /* out/input row stride = T*XD */
#define NPH 129

typedef __attribute__((ext_vector_type(8))) short short8;
typedef __attribute__((ext_vector_type(4))) float f32x4;

static const size_t GSTRIDE = (size_t)36 * 64 * 64 * 8;   // shorts per gate group (Bg)
static const size_t EPACK   = 4 * GSTRIDE;                // shorts per enc/dec pack
static const size_t CSTRIDE = (size_t)32 * 64 * 64 * 8;   // shorts per gate group (Wcb)

struct Phase {
  float spA, spB, nsA, nsB, qsA, qsB, q2sA, q2sB;
  int ebase, xe, xd, afrag;      // xd = combo Pn slot (decoder), -1 if none
  int hpA, hpB, nskip, qskip, q2skip;
  int anext, pnext, p2next, hout;
  int pfrag, pouti, pxout;       // pxout unused (kept for layout)
};
static_assert(sizeof(Phase) == 96, "phase size");

__device__ __forceinline__ unsigned short f2bf(float f) {
  union { float f; unsigned u; } c; c.f = f;
  unsigned u = c.u + (0x7fffu + ((c.u >> 16) & 1u));  // RNE; finite inputs
  return (unsigned short)(u >> 16);
}
__device__ __forceinline__ float sigm_(float x) { return 1.f / (1.f + __expf(-x)); }
__device__ __forceinline__ float tanh_(float x) { return 2.f / (1.f + __expf(-2.f * x)) - 1.f; }

__device__ __forceinline__ short8 cvt8(float4 a, float4 b) {
  short8 o;
  o[0] = (short)f2bf(a.x); o[1] = (short)f2bf(a.y); o[2] = (short)f2bf(a.z); o[3] = (short)f2bf(a.w);
  o[4] = (short)f2bf(b.x); o[5] = (short)f2bf(b.y); o[6] = (short)f2bf(b.z); o[7] = (short)f2bf(b.w);
  return o;
}

// ---- coherence-point accesses (cross-XCD exchange), no cache maintenance ----
__device__ __forceinline__ unsigned long long ld64_sys(const unsigned short* p) {
  return __hip_atomic_load((const unsigned long long*)p, __ATOMIC_RELAXED,
                           __HIP_MEMORY_SCOPE_SYSTEM);
}
__device__ __forceinline__ unsigned ld32_sys(const unsigned* p) {
  return __hip_atomic_load(p, __ATOMIC_RELAXED, __HIP_MEMORY_SCOPE_SYSTEM);
}
__device__ __forceinline__ void st32_sys(unsigned* p, unsigned v) {
  __hip_atomic_store(p, v, __ATOMIC_RELAXED, __HIP_MEMORY_SCOPE_SYSTEM);
}
union U128 { unsigned long long u[2]; short8 v; };
__device__ __forceinline__ short8 mk8(unsigned long long a, unsigned long long b) {
  U128 u; u.u[0] = a; u.u[1] = b; return u.v;
}
__device__ __forceinline__ void st_pair_bf(unsigned short* addr, int lane, unsigned short v) {
  unsigned other = (unsigned)__shfl_xor((int)(unsigned)v, 1);
  if ((lane & 1) == 0)
    st32_sys((unsigned*)addr, ((unsigned)v & 0xffffu) | (other << 16));
}

#define MFMA(a,b,c) __builtin_amdgcn_mfma_f32_16x16x32_bf16((a),(b),(c),0,0,0)

// ---------------- prep kernels ----------------
__global__ __launch_bounds__(256) void pack_gates(
    const float* __restrict__ eWih, const float* __restrict__ eWhh,
    const float* __restrict__ dWih, const float* __restrict__ dWhh,
    short* __restrict__ Bg)
{
  unsigned t = blockIdx.x * 256u + threadIdx.x;
  unsigned l  = t & 63u; t >>= 6;
  unsigned nf = t & 63u; t >>= 6;
  unsigned ks = t % 36u; t /= 36u;
  unsigned g  = t & 3u;  t >>= 2;
  if (t >= 2u) return;
  if ((g == 2u && ks >= 4u) || (g == 3u && ks < 4u)) return;
  const float* Wih = t ? dWih : eWih;
  const float* Whh = t ? dWhh : eWhh;
  int k = (int)(ks * 32u + (l >> 4) * 8u);
  int n = (int)(nf * 16u + (l & 15u));
  const float* src;
  if (g == 3u)      src = Whh + (size_t)(2048 + n) * HDIM + (k - XDIM);
  else if (g == 2u) src = Wih + (size_t)(2048 + n) * XDIM + k;
  else if (ks < 4u) src = Wih + (size_t)(g * HDIM + n) * XDIM + k;
  else              src = Whh + (size_t)(g * HDIM + n) * HDIM + (k - XDIM);
  float4 a = *(const float4*)src;
  float4 b = *(const float4*)(src + 4);
  size_t off = ((((size_t)t * 4u + g) * 36u + ks) * 64u + nf) * 64u + l;
  *(short8*)(Bg + off * 8u) = cvt8(a, b);
}

// W_combo = dWih(3 gates r,z,n) @ linW : [3][1024][1024], frag-packed
__global__ __launch_bounds__(256) void pack_combo(
    const float* __restrict__ dWih, const float* __restrict__ linW,
    short* __restrict__ Wcb)
{
  unsigned t = blockIdx.x * 256u + threadIdx.x;   // 3*32*64*64 = 393,216
  unsigned l  = t & 63u; t >>= 6;
  unsigned nf = t & 63u; t >>= 6;
  unsigned u  = t & 31u; t >>= 5;
  unsigned g  = t;
  if (g >= 3u) return;
  const int n = (int)(nf * 16u + (l & 15u));
  const int k = (int)(u * 32u + (l >> 4) * 8u);
  const float* wrow = dWih + ((size_t)g * 1024 + n) * XDIM;
  float acc[8] = {0,0,0,0,0,0,0,0};
  for (int m = 0; m < 128; ++m) {
    const float w = wrow[m];
    const float* lp = linW + (size_t)m * HDIM + k;
    float4 a = *(const float4*)lp;
    float4 b = *(const float4*)(lp + 4);
    acc[0] = fmaf(w, a.x, acc[0]); acc[1] = fmaf(w, a.y, acc[1]);
    acc[2] = fmaf(w, a.z, acc[2]); acc[3] = fmaf(w, a.w, acc[3]);
    acc[4] = fmaf(w, b.x, acc[4]); acc[5] = fmaf(w, b.y, acc[5]);
    acc[6] = fmaf(w, b.z, acc[6]); acc[7] = fmaf(w, b.w, acc[7]);
  }
  short8 o;
#pragma unroll
  for (int j = 0; j < 8; ++j) o[j] = (short)f2bf(acc[j]);
  *(short8*)(Wcb + (((size_t)g * 32 + u) * 64 + nf) * 512 + l * 8) = o;
}

__global__ __launch_bounds__(256) void pack_lin(const float* __restrict__ linW,
                                                short* __restrict__ Bl)
{
  unsigned t = blockIdx.x * 256u + threadIdx.x;
  unsigned l  = t & 63u; t >>= 6;
  unsigned nf = t & 7u;  t >>= 3;
  unsigned ks = t;
  if (ks >= 32u) return;
  int k = (int)(ks * 32u + (l >> 4) * 8u);
  int n = (int)(nf * 16u + (l & 15u));
  const float* src = linW + (size_t)n * HDIM + k;
  float4 a = *(const float4*)src;
  float4 b = *(const float4*)(src + 4);
  *(short8*)(Bl + (((size_t)ks * 8u + nf) * 64u + l) * 8u) = cvt8(a, b);
}

// bias: [e=0 enc][e=1 dec (no x; step 0)][e=2 dec + Wih·linb] x [4][1024]
__global__ __launch_bounds__(256) void pack_bias(
    const float* __restrict__ eIh, const float* __restrict__ eHh,
    const float* __restrict__ dIh, const float* __restrict__ dHh,
    const float* __restrict__ dWih, const float* __restrict__ linb,
    float* __restrict__ bias)
{
  unsigned t = blockIdx.x * 256u + threadIdx.x;
  if (t >= 12288u) return;
  unsigned n = t & 1023u, g = (t >> 10) & 3u, e = t >> 12;
  const float* bih = e ? dIh : eIh;
  const float* bhh = e ? dHh : eHh;
  float v;
  if (g == 0u)      v = bih[n] + bhh[n];
  else if (g == 1u) v = bih[HDIM + n] + bhh[HDIM + n];
  else if (g == 2u) v = bih[2 * HDIM + n];
  else              v = bhh[2 * HDIM + n];
  if (e == 2u && g < 3u) {
    const float* wr = dWih + ((size_t)g * 1024 + n) * XDIM;
    float s = 0.f;
    for (int m = 0; m < 128; ++m) s = fmaf(wr[m], linb[m], s);
    v += s;
  }
  bias[t] = v;
}

// enc input -> frag-major bf16: Xe[i][ks4][lq4][row256][8]
__global__ __launch_bounds__(256) void pack_x(const float* __restrict__ in,
                                              unsigned short* __restrict__ Xe)
{
  unsigned t = blockIdx.x * 256u + threadIdx.x;
  unsigned row = t & 255u; t >>= 8;
  unsigned lq  = t & 3u;   t >>= 2;
  unsigned ks  = t & 3u;   t >>= 2;
  unsigned i   = t;
  if (i >= 64u) return;
  const float* src = in + (size_t)row * ORS + i * 128u + ks * 32u + lq * 8u;
  float4 a = *(const float4*)src;
  float4 b = *(const float4*)(src + 4);
  *(short8*)(Xe + ((((size_t)i * 4u + ks) * 4u + lq) * 256u + row) * 8u) = cvt8(a, b);
}

// ---------------- phase-table builder (1 thread) ----------------
__device__ __forceinline__ int mkslot(int s) { return s % 11; }

__device__ void blank_phase(Phase& ph) {
  ph.spA = ph.spB = ph.nsA = ph.nsB = ph.qsA = ph.qsB = ph.q2sA = ph.q2sB = 0.f;
  ph.ebase = 0; ph.xe = -1; ph.xd = -1; ph.afrag = -1;
  ph.hpA = ph.hpB = ph.nskip = ph.qskip = ph.q2skip = 0;
  ph.anext = ph.pnext = ph.p2next = -1; ph.hout = -1;
  ph.pfrag = -1; ph.pouti = -1; ph.pxout = -1;
}

__global__ void setup_phases(Phase* __restrict__ phs, unsigned* __restrict__ arr) {
  const int t = threadIdx.x;
  for (int k = t; k < 1024; k += 64) arr[k] = 0u;
  if (t != 0) return;

  // numpy-legacy MT19937, RandomState(0)
  unsigned mt[624];
  mt[0] = 0u;
  for (int i = 1; i < 624; ++i)
    mt[i] = 1812433253u * (mt[i - 1] ^ (mt[i - 1] >> 30)) + (unsigned)i;
  for (int i = 0; i < 624; ++i) {
    unsigned y = (mt[i] & 0x80000000u) | (mt[(i + 1) % 624] & 0x7fffffffu);
    unsigned v = mt[(i + 397) % 624] ^ (y >> 1);
    mt[i] = (y & 1u) ? (v ^ 0x9908b0dfu) : v;
  }
  int mti = 0;
  float ew[64][2], dw[64][2];
  for (int e = 0; e < 2; ++e) {
    for (int i = 0; i < 64; ++i) {
      unsigned y = mt[mti++];
      y ^= y >> 11; y ^= (y << 7) & 0x9d2c5680u; y ^= (y << 15) & 0xefc60000u; y ^= y >> 18;
      int w1 = (int)(y & 1u);
      int w2 = 1;
      if (w1 != 0) {
        unsigned z = mt[mti++];
        z ^= z >> 11; z ^= (z << 7) & 0x9d2c5680u; z ^= (z << 15) & 0xefc60000u; z ^= z >> 18;
        w2 = (int)(z & 1u);
      }
      if (e == 0) { ew[i][0] = (float)w1; ew[i][1] = (float)w2; }
      else        { dw[i][0] = (float)w1; dw[i][1] = (float)w2; }
    }
  }

  bool anull = true;
  // ---- encoder phases 0..63 ----
  for (int i = 0; i < 64; ++i) {
    Phase ph; blank_phase(ph);
    ph.ebase = 0; ph.xe = i;
    ph.hout = mkslot(i);
    if (i >= 1 && !anull) ph.afrag = i & 1;
    ph.hpA = mkslot(i >= 1 ? i - 1 : 0);
    ph.spA = i ? ew[i][0] : 0.f;
    if (i == 3)       { ph.hpB = mkslot(1);      ph.spB = ew[i][1]; }
    else if (i == 4)  { ph.hpB = mkslot(3);      ph.spB = ew[i][1]; }
    else if (i >= 10) { ph.hpB = mkslot(i - 10); ph.spB = ew[i][1]; }
    if (i < 63) {
      int n = i + 1;
      ph.anext = n & 1;
      if (n == 4) ph.nsA = ew[4][0] + ew[4][1];
      else {
        ph.nsA = ew[n][0];
        if (n == 3)       { ph.nsB = ew[3][1]; ph.nskip = mkslot(1); }
        else if (n >= 10) { ph.nsB = ew[n][1]; ph.nskip = mkslot(n - 10); }
      }
    } else {  // enc63 -> An[dec0] (global step 64, slot 0), Pn[0]
      ph.anext = 0; ph.nsA = 2.f * dw[0][0];
      ph.pnext = 0; ph.qsA = 2.f;
    }
    if (ph.anext >= 0) {
      anull = (ph.nsA == 0.f && ph.nsB == 0.f);
      if (anull) ph.anext = -1;
    }
    phs[i] = ph;
  }
  // ---- decoder phases ----
  for (int i = 0; i < 64; ++i) {
    int p = 64 + i + (i >= 5 ? 1 : 0);
    int s = 64 + i;
    Phase ph; blank_phase(ph);
    ph.ebase = (i == 0) ? 4096 : 8192;
    ph.xd = i ? (i - 1) & 3 : -1;         // combo operand: Pn slot (j-1)&3
    ph.hout = mkslot(s);
    if (!anull) ph.afrag = i & 1;          // global step parity: (64+i)&1 = i&1
    ph.hpA = mkslot(i ? s - 1 : 63);
    ph.spA = i ? dw[i][0] : 2.f * dw[0][0];
    if (i == 3)       { ph.hpB = mkslot(64 + 1);  ph.spB = dw[i][1]; }
    else if (i == 4)  { ph.hpB = mkslot(64 + 3);  ph.spB = dw[i][1]; }
    else if (i >= 10) { ph.hpB = mkslot(s - 10);  ph.spB = dw[i][1]; }
    if (i < 63) {
      int n = i + 1;
      ph.anext = n & 1;
      if (n == 4) ph.nsA = dw[4][0] + dw[4][1];
      else {
        ph.nsA = dw[n][0];
        if (n == 3)       { ph.nsB = dw[3][1]; ph.nskip = mkslot(64 + 1); }
        else if (n >= 10) { ph.nsB = dw[n][1]; ph.nskip = mkslot(64 + n - 10); }
      }
    }
    // Pn producers
    if (i == 2)      { ph.pnext = 3; ph.qsA = 2.f; }
    else if (i == 3) { /* Pn[4] deferred to dec4 */ }
    else if (i == 4) { ph.pnext = 1; ph.qsA = 1.f;
                       ph.p2next = 0; ph.q2sA = 1.f; ph.q2sB = 1.f;
                       ph.q2skip = mkslot(64 + 3); }
    else if (i < 63) {
      int n = i + 1;
      ph.pnext = n & 3; ph.qsA = 1.f;
      if (n == 2)       { ph.qsB = 1.f; ph.qskip = mkslot(64 + 0); }
      else if (n >= 10) { ph.qsB = 1.f; ph.qskip = mkslot(64 + n - 10); }
    }
    if (ph.anext >= 0) {
      bool z = (ph.nsA == 0.f && ph.nsB == 0.f);
      if (z) ph.anext = -1;
      anull = z;
    }
    if (i != 4) { ph.pfrag = i & 3; ph.pouti = i; }
    phs[p] = ph;
    if (i == 4) {
      Phase pp; blank_phase(pp);
      pp.pfrag = 0; pp.pouti = 4;   // proj4 standalone phase (Pn[4] slot 0)
      phs[69] = pp;
    }
  }
}

// ---------------- persistent kernel ----------------
// Block = 32 rows x 32 cols, 8 waves (pure K-split). Decoder x-contribution is
// folded through W_combo and consumes Pn[i-1] (2 phases old -> PRE-POLL staging).
// proj feeds only out[] -> runs AFTER the flag (shadow work).
__global__ __launch_bounds__(512, 1) void rae_persist(
    const Phase* __restrict__ phs,
    const unsigned short* __restrict__ Xe,
    const unsigned short* __restrict__ BgE,
    const unsigned short* __restrict__ BgD,
    const unsigned short* __restrict__ Wcb,
    const unsigned short* __restrict__ Blin,
    const float* __restrict__ bias,
    const float* __restrict__ linb,
    float* __restrict__ hring,
    unsigned short* __restrict__ AnB,
    unsigned short* __restrict__ PnB,
    float* __restrict__ out,
    unsigned* __restrict__ arr)
{
  const int tid = threadIdx.x;
  const int lane = tid & 63;
  const int wave = tid >> 6;
  const int l15 = lane & 15, lq = lane >> 4;
  const int bid = blockIdx.x;
  const int mt = bid >> 5, ns = bid & 31;    // bid%8 == ns%8 -> XCD-pinned B slice
  const int nf0 = ns * 2;
  const int R0 = mt * 32;
  const int hu0 = (wave < 4) ? wave + 8 : wave;   // h units: hu0 + 8k
  const int cb  = (wave < 4) ? wave + 4 : wave - 4; // combo units: cb + 8k

  __shared__ f32x4 red[8][2][8][64];   // 128 KiB: slots 0..5 = acc, 6..7 = g2
  __shared__ f32x4 red3[8][2][64];     // 16 KiB : proj partials

#pragma unroll 1
  for (int p = 0; p < NPH; ++p) {
    const Phase ph = phs[p];             // uniform read (L2-resident table)
    const bool cell = (ph.hout >= 0);
    const bool isProj = (ph.pfrag >= 0) && (ns < 8);
    const bool hasA = cell && (ph.afrag >= 0);
    const bool hasC = cell && (ph.xd >= 0);
    const unsigned short* Bg = (p < 64) ? BgE : BgD;
    const float* bias4 = bias + ph.ebase;

    const f32x4 zero = {0.f, 0.f, 0.f, 0.f};
    f32x4 acc[2][6];
    f32x4 g2a[2][2];
#pragma unroll
    for (int rf = 0; rf < 2; ++rf) {
#pragma unroll
      for (int s = 0; s < 6; ++s) acc[rf][s] = zero;
      g2a[rf][0] = zero; g2a[rf][1] = zero;
    }

    // ---- pre-poll: epilogue prefetch (block-private cached hring) ----
    float hpv[4] = {0,0,0,0}, nskv[4] = {0,0,0,0},
          qskv[4] = {0,0,0,0}, q2skv[4] = {0,0,0,0};
    if (cell && wave < 4) {
      const int erf = wave >> 1, enf = wave & 1;
      const int colE = ns * 32 + enf * 16 + l15;
      const float* hpA = hring + (size_t)ph.hpA * 262144u;
      const float* hpB = hring + (size_t)ph.hpB * 262144u;
      const float* nsk = hring + (size_t)ph.nskip * 262144u;
      const float* qsk = hring + (size_t)ph.qskip * 262144u;
      const float* q2k = hring + (size_t)ph.q2skip * 262144u;
#pragma unroll
      for (int q = 0; q < 4; ++q) {
        const size_t o = (size_t)(R0 + erf * 16 + lq * 4 + q) * HDIM + colE;
        float hv = 0.f;
        if (ph.spA != 0.f) hv = ph.spA * hpA[o];
        if (ph.spB != 0.f) hv = fmaf(ph.spB, hpB[o], hv);
        hpv[q] = hv;
        if (ph.anext >= 0 && ph.nsB != 0.f) nskv[q] = nsk[o];
        if (ph.pnext >= 0 && ph.qsB != 0.f) qskv[q] = qsk[o];
        if (ph.p2next >= 0) q2skv[q] = q2k[o];
      }
    }
    // ---- pre-poll: encoder x (static Xe; accumulates into acc/g2a) ----
    if (cell && wave < 4 && ph.xe >= 0) {
      const unsigned short* xf = Xe + (size_t)ph.xe * 32768u;
      const unsigned short* bb = Bg + ((size_t)(wave * 64 + nf0) * 64 + lane) * 8;
      short8 b00 = *(const short8*)(bb);
      short8 b01 = *(const short8*)(bb + 512);
      short8 b10 = *(const short8*)(bb + GSTRIDE);
      short8 b11 = *(const short8*)(bb + GSTRIDE + 512);
      short8 b20 = *(const short8*)(bb + 2 * GSTRIDE);
      short8 b21 = *(const short8*)(bb + 2 * GSTRIDE + 512);
#pragma unroll
      for (int rf = 0; rf < 2; ++rf) {
        const unsigned short* a = xf + (((size_t)(wave * 4 + lq)) * 256 + R0 + rf * 16 + l15) * 8;
        short8 av = *(const short8*)a;
        acc[rf][0] = MFMA(av, b00, acc[rf][0]);
        acc[rf][1] = MFMA(av, b01, acc[rf][1]);
        acc[rf][2] = MFMA(av, b10, acc[rf][2]);
        acc[rf][3] = MFMA(av, b11, acc[rf][3]);
        g2a[rf][0] = MFMA(av, b20, g2a[rf][0]);
        g2a[rf][1] = MFMA(av, b21, g2a[rf][1]);
      }
    }
    // ---- pre-poll: stage combo A loads (Pn[i-1], settled 2 phases ago) ----
    unsigned long long ca0[4][2], ca1[4][2];
    if (hasC) {
      const unsigned short* cf = PnB + (size_t)ph.xd * 262144u;
#pragma unroll
      for (int k = 0; k < 4; ++k) {
        const int cu = cb + 8 * k;
#pragma unroll
        for (int rf = 0; rf < 2; ++rf) {
          const unsigned short* a =
              cf + (((size_t)(cu * 4 + lq)) * 256 + R0 + rf * 16 + l15) * 8;
          ca0[k][rf] = ld64_sys(a); ca1[k][rf] = ld64_sys(a + 4);
        }
      }
    }

    // ---- poll ----
    if (p > 0) {
      int guard = 0;
      for (;;) {
        unsigned v = ld32_sys(&arr[(mt << 5) + (lane & 31)]);
        if (__all(v >= (unsigned)p)) break;
        if (++guard > (1 << 22)) break;   // safety: fail-validate instead of hang
      }
    }

    // ---- post-poll: stage An + proj-Pn coherent loads (one RT umbrella) ----
    unsigned long long ha0[4][2], ha1[4][2];
    if (hasA) {
      const unsigned short* af = AnB + (size_t)ph.afrag * 262144u;
#pragma unroll
      for (int k = 0; k < 4; ++k) {
        const int u = hu0 + 8 * k;
#pragma unroll
        for (int rf = 0; rf < 2; ++rf) {
          const unsigned short* b =
              af + (((size_t)((u - 4) * 4 + lq)) * 256 + R0 + rf * 16 + l15) * 8;
          ha0[k][rf] = ld64_sys(b); ha1[k][rf] = ld64_sys(b + 4);
        }
      }
    }
    unsigned long long pq0[4][2], pq1[4][2];
    if (isProj) {
      const unsigned short* pf = PnB + (size_t)ph.pfrag * 262144u;
#pragma unroll
      for (int k0 = 0; k0 < 4; ++k0) {
        const int ks = wave * 4 + k0;
#pragma unroll
        for (int rf = 0; rf < 2; ++rf) {
          const unsigned short* a =
              pf + (((size_t)(ks * 4 + lq)) * 256 + R0 + rf * 16 + l15) * 8;
          pq0[k0][rf] = ld64_sys(a); pq1[k0][rf] = ld64_sys(a + 4);
        }
      }
    }

    // ---- combo MFMAs (A staged pre-poll -> ready; B inline from L2) ----
    if (hasC) {
#pragma unroll
      for (int k = 0; k < 4; ++k) {
        const int cu = cb + 8 * k;
        const unsigned short* bb = Wcb + ((size_t)(cu * 64 + nf0) * 64 + lane) * 8;
        short8 c00 = *(const short8*)(bb);
        short8 c01 = *(const short8*)(bb + 512);
        short8 c10 = *(const short8*)(bb + CSTRIDE);
        short8 c11 = *(const short8*)(bb + CSTRIDE + 512);
        short8 c20 = *(const short8*)(bb + 2 * CSTRIDE);
        short8 c21 = *(const short8*)(bb + 2 * CSTRIDE + 512);
#pragma unroll
        for (int rf = 0; rf < 2; ++rf) {
          short8 av = mk8(ca0[k][rf], ca1[k][rf]);
          acc[rf][0] = MFMA(av, c00, acc[rf][0]);
          acc[rf][1] = MFMA(av, c01, acc[rf][1]);
          acc[rf][2] = MFMA(av, c10, acc[rf][2]);
          acc[rf][3] = MFMA(av, c11, acc[rf][3]);
          g2a[rf][0] = MFMA(av, c20, g2a[rf][0]);
          g2a[rf][1] = MFMA(av, c21, g2a[rf][1]);
        }
      }
    }
    // ---- h MFMAs ----
    if (hasA) {
#pragma unroll
      for (int k = 0; k < 4; ++k) {
        const int u = hu0 + 8 * k;
        const unsigned short* bb = Bg + ((size_t)(u * 64 + nf0) * 64 + lane) * 8;
        short8 b00 = *(const short8*)(bb);
        short8 b01 = *(const short8*)(bb + 512);
        short8 b10 = *(const short8*)(bb + GSTRIDE);
        short8 b11 = *(const short8*)(bb + GSTRIDE + 512);
        short8 b30 = *(const short8*)(bb + 3 * GSTRIDE);
        short8 b31 = *(const short8*)(bb + 3 * GSTRIDE + 512);
#pragma unroll
        for (int rf = 0; rf < 2; ++rf) {
          short8 av = mk8(ha0[k][rf], ha1[k][rf]);
          acc[rf][0] = MFMA(av, b00, acc[rf][0]);
          acc[rf][1] = MFMA(av, b01, acc[rf][1]);
          acc[rf][2] = MFMA(av, b10, acc[rf][2]);
          acc[rf][3] = MFMA(av, b11, acc[rf][3]);
          acc[rf][4] = MFMA(av, b30, acc[rf][4]);
          acc[rf][5] = MFMA(av, b31, acc[rf][5]);
        }
      }
    }

    // ---- partial writes ----
    if (cell) {
#pragma unroll
      for (int rf = 0; rf < 2; ++rf) {
#pragma unroll
        for (int s = 0; s < 6; ++s) red[wave][rf][s][lane] = acc[rf][s];
        red[wave][rf][6][lane] = g2a[rf][0];
        red[wave][rf][7][lane] = g2a[rf][1];
      }
    }
    __syncthreads();   // sync1

    // ---- epilogue (waves 0-3) ----
    if (cell && wave < 4) {
      const int erf = wave >> 1, enf = wave & 1;
      f32x4 S0 = zero, S1 = zero, S3 = zero, S2 = zero;
#pragma unroll
      for (int w = 0; w < 8; ++w) {
        S0 += red[w][erf][0 + enf][lane];
        S1 += red[w][erf][2 + enf][lane];
        S3 += red[w][erf][4 + enf][lane];
        S2 += red[w][erf][6 + enf][lane];
      }
      const int colE = ns * 32 + enf * 16 + l15;
      const float br = bias4[colE],            bz = bias4[HDIM + colE];
      const float bi = bias4[2 * HDIM + colE], bh = bias4[3 * HDIM + colE];
      const int fa = (colE >> 3) * 2048 + (colE & 7);
      float* hout = hring + (size_t)ph.hout * 262144u;
      unsigned short* anx = ph.anext  >= 0 ? AnB + (size_t)ph.anext  * 262144u : nullptr;
      unsigned short* pnx = ph.pnext  >= 0 ? PnB + (size_t)ph.pnext  * 262144u : nullptr;
      unsigned short* p2x = ph.p2next >= 0 ? PnB + (size_t)ph.p2next * 262144u : nullptr;
#pragma unroll
      for (int q = 0; q < 4; ++q) {
        const int row = R0 + erf * 16 + lq * 4 + q;
        const float r  = sigm_(S0[q] + br);
        const float z  = sigm_(S1[q] + bz);
        const float nv = tanh_(S2[q] + bi + r * (S3[q] + bh));
        const float h  = (1.f - z) * nv + z * hpv[q];
        if (anx) st_pair_bf(anx + fa + row * 8, lane, f2bf(ph.nsA * h + ph.nsB * nskv[q]));
        if (pnx) st_pair_bf(pnx + fa + row * 8, lane, f2bf(ph.qsA * h + ph.qsB * qskv[q]));
        if (p2x) st_pair_bf(p2x + fa + row * 8, lane, f2bf(ph.q2sA * h + ph.q2sB * q2skv[q]));
        hout[(size_t)row * HDIM + colE] = h;
      }
    }

    // ---- drain + flag (proj no longer gates the chain) ----
    asm volatile("s_waitcnt vmcnt(0)" ::: "memory");
    __syncthreads();   // sync2
    if (tid == 0) st32_sys(&arr[(mt << 5) + ns], (unsigned)(p + 1));

    // ---- proj shadow work (only out[] depends on it) ----
    if (isProj) {
      f32x4 pacc0 = zero, pacc1 = zero;
#pragma unroll
      for (int k0 = 0; k0 < 4; ++k0) {
        const int ks = wave * 4 + k0;
        short8 b = *(const short8*)(Blin + (((size_t)ks * 8 + ns) * 64 + lane) * 8);
        pacc0 = MFMA(mk8(pq0[k0][0], pq1[k0][0]), b, pacc0);
        pacc1 = MFMA(mk8(pq0[k0][1], pq1[k0][1]), b, pacc1);
      }
      red3[wave][0][lane] = pacc0;
      red3[wave][1][lane] = pacc1;
      __syncthreads();
      if (wave == 0) {
        const int col = ns * 16 + l15;
        const float lb = linb[col];
        float* po = out + (size_t)ph.pouti * XDIM;
#pragma unroll
        for (int rf = 0; rf < 2; ++rf) {
          f32x4 S = red3[0][rf][lane];
#pragma unroll
          for (int w = 1; w < 8; ++w) S += red3[w][rf][lane];
#pragma unroll
          for (int q = 0; q < 4; ++q) {
            const int row = R0 + rf * 16 + lq * 4 + q;
            po[(size_t)row * ORS + col] = S[q] + lb;
          }
        }
      }
    }
  }
  asm volatile("s_waitcnt vmcnt(0)" ::: "memory");
}

// ---------------- host ----------------
extern "C" void kernel_launch(void* const* d_in, const int* in_sizes, int n_in,
                              void* d_out, int out_size, void* d_ws, size_t ws_size,
                              hipStream_t stream)
{
  const float* input = (const float*)d_in[0];
  const float* eWih = (const float*)d_in[1];
  const float* eWhh = (const float*)d_in[2];
  const float* eBih = (const float*)d_in[3];
  const float* eBhh = (const float*)d_in[4];
  const float* dWih = (const float*)d_in[5];
  const float* dWhh = (const float*)d_in[6];
  const float* dBih = (const float*)d_in[7];
  const float* dBhh = (const float*)d_in[8];
  const float* linW = (const float*)d_in[9];
  const float* linb = (const float*)d_in[10];
  float* out = (float*)d_out;

  // workspace layout (bytes):
  //  BgE   @ 0           9,437,184
  //  BgD   @ 9,437,184   9,437,184
  //  Wcb   @18,874,368   6,291,456
  //  Blin  @25,165,824     262,144
  //  bias  @25,427,968      49,152   (3 x 4 x 1024 f32)
  //  hring @25,477,120  11,534,336   (11 x 256x1024 f32)
  //  Xe    @37,011,456   4,194,304
  //  AnB   @41,205,760   1,048,576   (2 slots)
  //  PnB   @42,254,336   2,097,152   (4 slots)
  //  phs   @44,351,488      16,384
  //  arr   @44,367,872       4,096   -> total 44,371,968 (<= proven 44,597,248)
  if (ws_size < 44371968u) return;
  char* ws = (char*)d_ws;
  short* BgE  = (short*)ws;
  short* BgD  = BgE + EPACK;
  short* Wcb  = (short*)(ws + 18874368u);
  short* Blin = (short*)(ws + 25165824u);
  float* bias = (float*)(ws + 25427968u);
  float* hring = (float*)(ws + 25477120u);
  unsigned short* Xe  = (unsigned short*)(ws + 37011456u);
  unsigned short* AnB = (unsigned short*)(ws + 41205760u);
  unsigned short* PnB = (unsigned short*)(ws + 42254336u);
  Phase* phs = (Phase*)(ws + 44351488u);
  unsigned* arr = (unsigned*)(ws + 44367872u);

  pack_gates<<<4608, 256, 0, stream>>>(eWih, eWhh, dWih, dWhh, BgE);
  pack_combo<<<1536, 256, 0, stream>>>(dWih, linW, Wcb);
  pack_lin<<<64, 256, 0, stream>>>(linW, Blin);
  pack_bias<<<48, 256, 0, stream>>>(eBih, eBhh, dBih, dBhh, dWih, linb, bias);
  pack_x<<<1024, 256, 0, stream>>>(input, Xe);
  setup_phases<<<1, 64, 0, stream>>>(phs, arr);

  rae_persist<<<256, 512, 0, stream>>>(
      phs, Xe, (const unsigned short*)BgE, (const unsigned short*)BgD,
      (const unsigned short*)Wcb, (const unsigned short*)Blin, bias, linb,
      hring, AnB, PnB, out, arr);
}